// Round 1
// baseline (673.726 us; speedup 1.0000x reference)
//
#include <hip/hip_runtime.h>
#include <hip/hip_bf16.h>
#include <math.h>

#define BATCH   32
#define DIM     4096
#define NH      32
#define NKV     8
#define GQ      4
#define HD      128
#define BS      16
#define MAXSEQ  2048
#define NBLK_TBL 128                 // MAX_SEQ / BLOCK_SIZE
#define SCALE_F 0.08838834764831845f // 128^-0.5

#define CHUNK_D   128                // split-K chunk for GEMMs
#define NCHUNK_D  32
#define ATT_CHUNK 256                // tokens per attention partial block
#define ATT_NCHUNK 8
#define ATT_TILE  32
#define QKV_COLS  6144               // 4096 q + 1024 k + 1024 v

// ---------------------------------------------------------------------------
// Split-K GEMM: partial[chunk][b][col] = sum_{d in chunk} X[b][d] * W[d][col]
// W is a column-concat of up to 3 row-major (D x n_i) matrices.
// Block: 256 thr = 32 colgrps (4 cols each) x 8 bgrps (4 batches each).
// CHUNK_D=128 -> 16KB LDS, grid 1536/1024 blocks (6/4 per CU).
// NEW: explicit 1-deep prefetch of the next 4 W rows so the 4 global loads
// of iteration j4+1 are in flight under j4's 64 FMAs (latency cover without
// relying on compiler modulo scheduling; keeps VGPR < 85 for 6 waves/SIMD).
// ---------------------------------------------------------------------------
__global__ __launch_bounds__(256) void gemm_split(
    const float* __restrict__ X,
    const float* __restrict__ W0, int ld0, int n0,
    const float* __restrict__ W1, int ld1, int n1,
    const float* __restrict__ W2, int ld2, int n2,
    int OT, float* __restrict__ partial)
{
    __shared__ float xs[BATCH][CHUNK_D];   // 16 KB
    const int tid = threadIdx.x;
    const int colbase = blockIdx.x * 128;
    const int d0 = blockIdx.y * CHUNK_D;

    // stage x[:, d0:d0+128] into LDS, coalesced float4
    #pragma unroll
    for (int rep = 0; rep < 4; ++rep) {
        int f4 = rep * 256 + tid;          // 0..1023 (32 rows x 32 f4)
        int b  = f4 >> 5;
        int j  = (f4 & 31) << 2;
        *(float4*)&xs[b][j] = *(const float4*)(X + b * DIM + d0 + j);
    }
    __syncthreads();

    const float* W; int ld, off;
    if (colbase < n0)           { W = W0; ld = ld0; off = colbase; }
    else if (colbase < n0 + n1) { W = W1; ld = ld1; off = colbase - n0; }
    else                        { W = W2; ld = ld2; off = colbase - n0 - n1; }

    const int colgrp = tid & 31;
    const int bgrp   = tid >> 5;
    const float* Wp = W + off + colgrp * 4;

    float acc[4][4];
    #pragma unroll
    for (int i = 0; i < 4; ++i)
        #pragma unroll
        for (int j = 0; j < 4; ++j) acc[i][j] = 0.f;

    float4 w0 = *(const float4*)(Wp + (size_t)(d0 + 0) * ld);
    float4 w1 = *(const float4*)(Wp + (size_t)(d0 + 1) * ld);
    float4 w2 = *(const float4*)(Wp + (size_t)(d0 + 2) * ld);
    float4 w3 = *(const float4*)(Wp + (size_t)(d0 + 3) * ld);

    for (int j4 = 0; j4 < CHUNK_D / 4; ++j4) {
        float4 n0, n1, n2, n3;
        if (j4 + 1 < CHUNK_D / 4) {
            const int dn = d0 + (j4 + 1) * 4;
            n0 = *(const float4*)(Wp + (size_t)(dn + 0) * ld);
            n1 = *(const float4*)(Wp + (size_t)(dn + 1) * ld);
            n2 = *(const float4*)(Wp + (size_t)(dn + 2) * ld);
            n3 = *(const float4*)(Wp + (size_t)(dn + 3) * ld);
        } else { n0 = w0; n1 = w1; n2 = w2; n3 = w3; }
        #pragma unroll
        for (int bb = 0; bb < 4; ++bb) {
            float4 xv = *(const float4*)&xs[bgrp * 4 + bb][j4 * 4];
            acc[bb][0] += xv.x * w0.x + xv.y * w1.x + xv.z * w2.x + xv.w * w3.x;
            acc[bb][1] += xv.x * w0.y + xv.y * w1.y + xv.z * w2.y + xv.w * w3.y;
            acc[bb][2] += xv.x * w0.z + xv.y * w1.z + xv.z * w2.z + xv.w * w3.z;
            acc[bb][3] += xv.x * w0.w + xv.y * w1.w + xv.z * w2.w + xv.w * w3.w;
        }
        w0 = n0; w1 = n1; w2 = n2; w3 = n3;
    }

    const int chunk = blockIdx.y;
    #pragma unroll
    for (int bb = 0; bb < 4; ++bb) {
        int b = bgrp * 4 + bb;
        float4 o = make_float4(acc[bb][0], acc[bb][1], acc[bb][2], acc[bb][3]);
        *(float4*)(partial + ((size_t)chunk * BATCH + b) * OT + colbase + colgrp * 4) = o;
    }
}

// ---------------------------------------------------------------------------
// Reduce QKV partials, apply RoPE to q and k.
// NEW: k/v for the new token go to WORKSPACE (knew/vnew), NOT to the caches.
// d_in is never written by this implementation -> harness need not restore
// the 537 MB of KV cache between iterations.
// Grid (BATCH, 6): seg 0..3 = q heads, seg 4 = k, seg 5 = v.
// ---------------------------------------------------------------------------
__global__ __launch_bounds__(256) void rope_qkv(
    const float* __restrict__ qkvp,   // [NCHUNK_D][BATCH][6144]
    const int* __restrict__ ctxlen,
    float* __restrict__ q_out,        // [BATCH][4096]
    float* __restrict__ knew,         // [BATCH][NKV][HD]
    float* __restrict__ vnew)         // [BATCH][NKV][HD]
{
    __shared__ float buf[1024];
    const int b = blockIdx.x, seg = blockIdx.y, tid = threadIdx.x;
    const int cbase = seg * 1024;
    for (int c = tid; c < 1024; c += 256) {
        float s = 0.f;
        #pragma unroll
        for (int ch = 0; ch < NCHUNK_D; ++ch)
            s += qkvp[((size_t)ch * BATCH + b) * QKV_COLS + cbase + c];
        buf[c] = s;
    }
    __syncthreads();
    const int pos  = ctxlen[b] - 1;
    const float fpos = (float)pos;
    const float NEG_LN_BASE_OVER_HALF = -0.14391156831212787f; // -ln(10000)/64

    if (seg < 4) {           // 8 q heads, rope
        for (int p = tid; p < 8 * 64; p += 256) {
            int h = p >> 6, i = p & 63;
            float x1 = buf[h * HD + i];
            float x2 = buf[h * HD + i + 64];
            float ang = fpos * __expf(NEG_LN_BASE_OVER_HALF * (float)i);
            float sn, cs;
            __sincosf(ang, &sn, &cs);
            q_out[b * 4096 + cbase + h * HD + i]      = x1 * cs - x2 * sn;
            q_out[b * 4096 + cbase + h * HD + i + 64] = x1 * sn + x2 * cs;
        }
    } else if (seg == 4) {   // k: rope -> workspace
        for (int p = tid; p < NKV * 64; p += 256) {
            int kv = p >> 6, i = p & 63;
            float x1 = buf[kv * HD + i];
            float x2 = buf[kv * HD + i + 64];
            float ang = fpos * __expf(NEG_LN_BASE_OVER_HALF * (float)i);
            float sn, cs;
            __sincosf(ang, &sn, &cs);
            knew[((size_t)b * NKV + kv) * HD + i]      = x1 * cs - x2 * sn;
            knew[((size_t)b * NKV + kv) * HD + i + 64] = x1 * sn + x2 * cs;
        }
    } else {                 // v -> workspace
        for (int p = tid; p < NKV * HD; p += 256)
            vnew[(size_t)b * NKV * HD + p] = buf[p];
    }
}

// ---------------------------------------------------------------------------
// Flash-decode attention partial. Grid (B, NKV, ATT_NCHUNK); block 256.
// Wave w = head w (GQ=4). Online softmax fully in registers via shfl_xor.
// NEW vs prev round:
//  - scores use ALL 64 lanes: 2 lanes/token (lane>>5 picks dim-half), 16
//    b128 LDS reads/lane instead of 32, + one shfl_xor(32) combine. The 132f
//    K row pad keeps the 64-lane b128 read exactly uniform (8 words/bank).
//  - PV fully unrolled at nt==32 with 2 independent accumulators (chain 16).
//  - token pos is sourced from knew/vnew workspace during staging (caches
//    are read-only now).
//  - empty chunks return WITHOUT writing; attn_reduce is ctx-aware.
// LDS 35.4KB -> 4 blocks/CU.
// Partial layout per (b,kv,c): [4 heads][132] = o[0:128], m@128, l@129, pad.
// ---------------------------------------------------------------------------
__global__ __launch_bounds__(256) void attn_partial(
    const float* __restrict__ q,      // [BATCH][4096]
    const float* __restrict__ knew, const float* __restrict__ vnew,
    const float* __restrict__ kcache, const float* __restrict__ vcache,
    const int* __restrict__ btab, const int* __restrict__ ctxlen,
    float* __restrict__ part)
{
    const int b = blockIdx.x, kv = blockIdx.y, c = blockIdx.z;
    const int ctx = ctxlen[b];
    const int start = c * ATT_CHUNK;
    if (start >= ctx) return;                 // reducer skips invalid chunks
    const int end = min(ctx, start + ATT_CHUNK);
    const int pos = ctx - 1;
    const int tid = threadIdx.x;

    __shared__ float Ks[ATT_TILE][132];   // 16.9 KB
    __shared__ float Vs[ATT_TILE][128];   // 16 KB
    __shared__ float qs[4][HD];           // 2 KB
    __shared__ float p_lds[4][ATT_TILE];  // 0.5 KB

    for (int i = tid; i < 4 * HD; i += 256)
        qs[i >> 7][i & 127] = q[b * 4096 + kv * GQ * HD + i];

    const int h    = tid >> 6;   // wave index == head
    const int lane = tid & 63;
    const int t_l  = lane & 31;  // token this lane scores
    const int half = lane >> 5;  // dim-half this lane dots

    float m_run = -1e30f, l_run = 0.f;             // replicated across wave
    float2 oa = make_float2(0.f, 0.f);             // dims 2*lane, 2*lane+1
    float2 ob = make_float2(0.f, 0.f);

    for (int t0 = start; t0 < end; t0 += ATT_TILE) {
        const int nt = min(ATT_TILE, end - t0);
        // stage K,V tiles (coalesced float4); all 256 threads
        for (int idx = tid; idx < nt * 32; idx += 256) {
            int tt = idx >> 5, f4 = idx & 31;
            int tok = t0 + tt;
            const float* ksrc; const float* vsrc;
            if (tok == pos) {                       // new token from workspace
                size_t nb = ((size_t)b * NKV + kv) * HD;
                ksrc = knew + nb; vsrc = vnew + nb;
            } else {
                int slot = btab[b * NBLK_TBL + (tok >> 4)] * BS + (tok & 15);
                size_t base = ((size_t)slot * NKV + kv) * HD;
                ksrc = kcache + base; vsrc = vcache + base;
            }
            *(float4*)&Ks[tt][f4 * 4] = *(const float4*)(ksrc + f4 * 4);
            *(float4*)&Vs[tt][f4 * 4] = *(const float4*)(vsrc + f4 * 4);
        }
        __syncthreads();

        // scores: lanes (t,0) and (t,32) each dot 64 dims of K[t] . q[h]
        float sum = 0.f;
        {
            const float* kr = &Ks[t_l][half * 64];
            const float* qr = &qs[h][half * 64];
            #pragma unroll
            for (int d4 = 0; d4 < 16; ++d4) {
                float4 kk = *(const float4*)(kr + d4 * 4);
                float4 qq = *(const float4*)(qr + d4 * 4);
                sum += kk.x * qq.x + kk.y * qq.y + kk.z * qq.z + kk.w * qq.w;
            }
        }
        sum += __shfl_xor(sum, 32);               // full dot on both halves
        float s = (t_l < nt) ? sum * SCALE_F : -1e30f;

        // wave-wide online softmax (halves are replicas -> 5-step reduces)
        float mt = s;
        #pragma unroll
        for (int off = 1; off < 32; off <<= 1)
            mt = fmaxf(mt, __shfl_xor(mt, off));
        float mn = fmaxf(m_run, mt);
        float al = __expf(m_run - mn);
        float p  = (t_l < nt) ? __expf(s - mn) : 0.f;
        float ps = p;
        #pragma unroll
        for (int off = 1; off < 32; off <<= 1)
            ps += __shfl_xor(ps, off);
        l_run = l_run * al + ps;
        m_run = mn;
        if (lane < ATT_TILE) p_lds[h][lane] = p;  // same-wave RAW, no barrier

        // PV: lane = dim-pair; 2 independent acc chains
        oa.x *= al; oa.y *= al; ob.x *= al; ob.y *= al;
        if (nt == ATT_TILE) {
            #pragma unroll
            for (int t = 0; t < ATT_TILE; t += 2) {
                float p0 = p_lds[h][t], p1 = p_lds[h][t + 1];
                float2 v0 = *(const float2*)&Vs[t][lane * 2];
                float2 v1 = *(const float2*)&Vs[t + 1][lane * 2];
                oa.x += p0 * v0.x; oa.y += p0 * v0.y;
                ob.x += p1 * v1.x; ob.y += p1 * v1.y;
            }
        } else {
            for (int t = 0; t < nt; ++t) {
                float pv = p_lds[h][t];
                float2 vv = *(const float2*)&Vs[t][lane * 2];
                oa.x += pv * vv.x; oa.y += pv * vv.y;
            }
        }
        __syncthreads();   // Ks/Vs safe to overwrite next tile
    }
    float* pp = part + ((size_t)(b * NKV + kv) * ATT_NCHUNK + c) * (4 * 132);
    *(float2*)(pp + h * 132 + lane * 2) = make_float2(oa.x + ob.x, oa.y + ob.y);
    if (lane == 0) {
        pp[h * 132 + 128] = m_run;
        pp[h * 132 + 129] = l_run;
    }
}

// ---------------------------------------------------------------------------
// Combine attention chunk partials -> attn_out[b][head*128+d]
// ctx-aware: only the ceil(ctx/256) chunks that were written are read
// (required now that invalid chunks are never initialized + ws is poisoned).
// ---------------------------------------------------------------------------
__global__ __launch_bounds__(128) void attn_reduce(
    const float* __restrict__ part, const int* __restrict__ ctxlen,
    float* __restrict__ attn_out)
{
    const int b = blockIdx.x, kv = blockIdx.y;
    const int d = threadIdx.x;  // 0..127
    const int nc = (ctxlen[b] + ATT_CHUNK - 1) / ATT_CHUNK;
    const float* base = part + (size_t)(b * NKV + kv) * ATT_NCHUNK * (4 * 132);
    #pragma unroll
    for (int h = 0; h < 4; ++h) {
        float M = -1e30f;
        for (int c2 = 0; c2 < nc; ++c2)
            M = fmaxf(M, base[c2 * (4 * 132) + h * 132 + 128]);
        float L = 0.f, o = 0.f;
        for (int c2 = 0; c2 < nc; ++c2) {
            float m = base[c2 * (4 * 132) + h * 132 + 128];
            float l = base[c2 * (4 * 132) + h * 132 + 129];
            float w = __expf(m - M);
            L += l * w;
            o += base[c2 * (4 * 132) + h * 132 + d] * w;
        }
        attn_out[b * 4096 + (kv * GQ + h) * HD + d] = o / L;
    }
}

// ---------------------------------------------------------------------------
// Reduce o-proj partials -> d_out.  Grid (BATCH, 4), 1024 cols per block.
// ---------------------------------------------------------------------------
__global__ __launch_bounds__(256) void final_reduce(
    const float* __restrict__ part, float* __restrict__ out)
{
    const int b = blockIdx.x;
    const int cb = blockIdx.y * 1024;
    for (int c = threadIdx.x; c < 1024; c += 256) {
        float s = 0.f;
        #pragma unroll
        for (int ch = 0; ch < NCHUNK_D; ++ch)
            s += part[((size_t)ch * BATCH + b) * DIM + cb + c];
        out[b * DIM + cb + c] = s;
    }
}

extern "C" void kernel_launch(void* const* d_in, const int* in_sizes, int n_in,
                              void* d_out, int out_size, void* d_ws, size_t ws_size,
                              hipStream_t stream)
{
    const float* x  = (const float*)d_in[0];
    const float* Wq = (const float*)d_in[1];
    const float* Wk = (const float*)d_in[2];
    const float* Wv = (const float*)d_in[3];
    const float* Wo = (const float*)d_in[4];
    const float* kc = (const float*)d_in[5];   // READ-ONLY now — no d_in writes
    const float* vc = (const float*)d_in[6];
    const int* bt  = (const int*)d_in[7];
    const int* ctx = (const int*)d_in[8];
    float* out = (float*)d_out;

    // workspace layout (floats), ~48 MB
    float* ws = (float*)d_ws;
    float* qkvp      = ws;                                   // 32*32*6144
    float* q_ws      = qkvp + (size_t)NCHUNK_D * BATCH * QKV_COLS;
    float* knew      = q_ws + (size_t)BATCH * 4096;          // 32*8*128
    float* vnew      = knew + (size_t)BATCH * NKV * HD;
    float* attn_part = vnew + (size_t)BATCH * NKV * HD;      // 2048*528
    float* attn_o    = attn_part + (size_t)BATCH * NKV * ATT_NCHUNK * 4 * 132;
    float* oprojp    = attn_o + (size_t)BATCH * 4096;        // 32*32*4096

    gemm_split<<<dim3(48, NCHUNK_D), 256, 0, stream>>>(
        x, Wq, 4096, 4096, Wk, 1024, 1024, Wv, 1024, 1024, QKV_COLS, qkvp);
    rope_qkv<<<dim3(32, 6), 256, 0, stream>>>(qkvp, ctx, q_ws, knew, vnew);
    attn_partial<<<dim3(BATCH, NKV, ATT_NCHUNK), 256, 0, stream>>>(
        q_ws, knew, vnew, kc, vc, bt, ctx, attn_part);
    attn_reduce<<<dim3(BATCH, NKV), 128, 0, stream>>>(attn_part, ctx, attn_o);
    gemm_split<<<dim3(32, NCHUNK_D), 256, 0, stream>>>(
        attn_o, Wo, 4096, 4096, nullptr, 0, 0, nullptr, 0, 0, DIM, oprojp);
    final_reduce<<<dim3(32, 4), 256, 0, stream>>>(oprojp, out);
}